// Round 4
// baseline (624.384 us; speedup 1.0000x reference)
//
#include <hip/hip_runtime.h>

#define BATCH 2048
#define HID 1024
#define FFN 4096
#define NEXP 8
#define MAXROWS 5120   // sum ceil(count_e/128)*128 <= 4096 + 8*127 -> round up
#define MTILES 40      // MAXROWS/128 (fallback path)
#define MT256 24       // max 256-row tiles: sum ceil(padlen_e/256) <= (5112+1024)/256 < 24

typedef __attribute__((ext_vector_type(8))) short short8;
typedef __attribute__((ext_vector_type(4))) float floatx4;

// fp32 -> bf16 round-to-nearest-even
static __device__ inline unsigned short f2bf(float f) {
    unsigned int u = __float_as_uint(f);
    unsigned int r = (u + 0x7fffu + ((u >> 16) & 1u)) >> 16;
    return (unsigned short)r;
}

static __device__ inline int load_idx(const int* idx32, int flat, int is32) {
    return is32 ? idx32[flat] : idx32[2 * flat];  // int64 little-endian low word
}

// async global -> LDS DMA, 16B per lane; LDS dest wave-uniform base + lane*16.
static __device__ inline void gload_lds16(const unsigned short* g, unsigned short* l) {
    __builtin_amdgcn_global_load_lds(
        (const __attribute__((address_space(1))) unsigned int*)g,
        (__attribute__((address_space(3))) unsigned int*)l,
        16, 0, 0);
}

// fused: detect int32/int64 layout, per-expert counts, padded prefix sum,
// and the 256-row tile table (256 tiles span 128-padded expert boundaries).
__global__ void route_all(const int* __restrict__ idx32, int* __restrict__ fmt,
                          int* __restrict__ counts, int* __restrict__ pbase,
                          int* __restrict__ cursor, int* __restrict__ mte,
                          int* __restrict__ mtr, int* __restrict__ ntiles) {
    __shared__ int s_cnt[NEXP];
    __shared__ int s_fmt;
    int t = threadIdx.x;  // 1024 threads
    if (t < NEXP) s_cnt[t] = 0;
    if (t == 0) s_fmt = 0;
    __syncthreads();
    int bad = 0;
    for (int i = t; i < BATCH; i += 1024)       // odd words of first BATCH values
        if (idx32[2 * i + 1] != 0) bad = 1;     // in-bounds for both layouts
    if (bad) atomicOr(&s_fmt, 1);               // nonzero odd word -> plain int32
    __syncthreads();
    int is32 = s_fmt;
    for (int b = t; b < BATCH; b += 1024) {
        int e0 = load_idx(idx32, 2 * b, is32);
        int e1 = load_idx(idx32, 2 * b + 1, is32);
        atomicAdd(&s_cnt[e0], 1);
        if (e1 != e0) atomicAdd(&s_cnt[e1], 1);
    }
    __syncthreads();
    if (t == 0) {
        fmt[0] = is32;
        int acc = 0;
        for (int e = 0; e < NEXP; e++) {
            counts[e] = s_cnt[e];
            pbase[e] = acc;
            cursor[e] = acc;
            acc += ((s_cnt[e] + 127) >> 7) << 7;
        }
        pbase[NEXP] = acc;
        int nt = 0;
        for (int e = 0; e < NEXP; e++) {
            int len = pbase[e + 1] - pbase[e];
            for (int j = 0; j < len; j += 256) {
                mte[nt] = e;
                mtr[nt] = pbase[e] + j;
                nt++;
            }
        }
        ntiles[0] = nt;
    }
}

__global__ void scatter_gather(const float* __restrict__ x, const float* __restrict__ rw,
                               const int* __restrict__ idx32, const int* __restrict__ fmt,
                               int* __restrict__ cursor, int* __restrict__ tids,
                               float* __restrict__ twt, unsigned short* __restrict__ Apk) {
    __shared__ int s_slot[2];
    __shared__ int s_n;
    int b = blockIdx.x;
    if (threadIdx.x == 0) {
        int is32 = fmt[0];
        int e0 = load_idx(idx32, 2 * b, is32);
        int e1 = load_idx(idx32, 2 * b + 1, is32);
        float w0 = rw[2 * b], w1 = rw[2 * b + 1];
        int n, ee[2];
        float ww[2];
        if (e0 == e1) { n = 1; ee[0] = e0; ww[0] = w0 + w1; }
        else { n = 2; ee[0] = e0; ww[0] = w0; ee[1] = e1; ww[1] = w1; }
        for (int j = 0; j < n; j++) {
            int slot = atomicAdd(&cursor[ee[j]], 1);
            s_slot[j] = slot;
            tids[slot] = b;
            twt[slot] = ww[j];
        }
        s_n = n;
    }
    __syncthreads();
    int n = s_n;
    const float4* src = (const float4*)(x + (size_t)b * HID);
    for (int j = 0; j < n; j++) {
        unsigned short* dst = Apk + (size_t)s_slot[j] * HID;
        #pragma unroll
        for (int r = 0; r < 2; r++) {
            int i = threadIdx.x + r * 128;
            float4 v = src[i];
            union { unsigned short u[4]; uint2 q; } p;
            p.u[0] = f2bf(v.x); p.u[1] = f2bf(v.y);
            p.u[2] = f2bf(v.z); p.u[3] = f2bf(v.w);
            *(uint2*)(dst + i * 4) = p.q;
        }
    }
}

// convert fp32 W[E][K][N] -> bf16 Wt[E][N][K] (transpose via 64x64 LDS tile)
__global__ void conv_transpose(const float* __restrict__ W, unsigned short* __restrict__ Wt,
                               int K, int N) {
    __shared__ unsigned short sT[64][65];
    int e = blockIdx.z;
    int kt = blockIdx.y * 64, nt = blockIdx.x * 64;
    const float* src = W + ((size_t)e * K + kt) * N + nt;
    #pragma unroll
    for (int i = 0; i < 4; i++) {
        int t = threadIdx.x + i * 256;          // 0..1023, 64 rows x 16 float4
        int r = t >> 4, c4 = (t & 15) * 4;
        float4 v = *(const float4*)(src + (size_t)r * N + c4);
        sT[c4 + 0][r] = f2bf(v.x);
        sT[c4 + 1][r] = f2bf(v.y);
        sT[c4 + 2][r] = f2bf(v.z);
        sT[c4 + 3][r] = f2bf(v.w);
    }
    __syncthreads();
    #pragma unroll
    for (int i = 0; i < 2; i++) {
        int u = threadIdx.x + i * 256;          // 0..511, 64 rows x 8 uint4
        int n = u >> 3, k8 = (u & 7) * 8;
        union { unsigned short h[8]; uint4 q; } p;
        #pragma unroll
        for (int j = 0; j < 8; j++) p.h[j] = sT[n][k8 + j];
        *(uint4*)(Wt + ((size_t)e * N + nt + n) * K + kt + k8) = p.q;
    }
}

// ---------------- 256x256 multi-phase counted-vmcnt GEMM (T2+T3+T4+T5) -----
// 512 threads = 8 waves (2M x 4N); per-wave output 128x64 (8x4 16x16 frags).
// BK=64, double-buffered 128KiB LDS, staged via global_load_lds width=16 with
// pre-swizzled GLOBAL source (LDS dest linear; 16B slot s of row r holds
// global k-slot s^(r&7); reads XOR the same way -> conflict-free ds_read_b128).
// Per K-tile: 4 quadrant phases {ds_read 8 frags; [stage 4 DMA]; barrier;
// lgkmcnt(0)+sched_barrier; setprio(1); 16 MFMA; setprio(0); barrier}.
// Tile t+1's 8 DMA issues are front-loaded into phases 0-1, so the single
// vmcnt(0) at phase 3 waits on loads issued >=2 phases earlier (no mid-
// compute drain -> the round-1 failure mode is avoided).
// Tiles come from an explicit (expert,row0) table since 256-row tiles span
// the 128-padded expert boundaries; GEMM1 stores are guarded to row<pbase[e+1].
template <int KTOT, int NTOT, bool SILU, int KSPLIT>
__global__ __launch_bounds__(512, 2) void gemm8p(
    const unsigned short* __restrict__ Abuf, const unsigned short* __restrict__ Bt,
    unsigned short* __restrict__ Hout, float* __restrict__ Out,
    const int* __restrict__ tids, const float* __restrict__ twt,
    const int* __restrict__ counts, const int* __restrict__ pbase,
    const int* __restrict__ mte, const int* __restrict__ mtr,
    const int* __restrict__ ntiles) {
    __shared__ __align__(16) unsigned short sA[2][256 * 64];
    __shared__ __align__(16) unsigned short sB[2][256 * 64];

    int bm = blockIdx.x;
    if (bm >= ntiles[0]) return;
    int e = mte[bm];
    int row0 = mtr[bm];
    int n0 = blockIdx.y * 256;
    constexpr int KCH = KTOT / KSPLIT;
    constexpr int NT = KCH / 64;
    int kb = blockIdx.z * KCH;

    int tid = threadIdx.x;
    int lane = tid & 63, wid = tid >> 6;
    int wm = wid >> 2, wn = wid & 3;
    int quad = lane >> 4, l16 = lane & 15;

    // staging map: 2048 16B-chunks per 256x64 tile; chunk c = j*512+wid*64+lane
    // -> LDS row c>>3, slot c&7; global source k-slot = slot ^ (row&7).
    size_t oA[4], oB[4];
    #pragma unroll
    for (int j = 0; j < 4; j++) {
        int c = j * 512 + wid * 64 + lane;
        int r = c >> 3, s = c & 7;
        int ra = row0 + r;
        if (ra > MAXROWS - 1) ra = MAXROWS - 1;   // boundary-tile overhang clamp
        oA[j] = (size_t)ra * KTOT * 2 + (size_t)((s ^ (r & 7)) * 16) + (size_t)kb * 2;
        oB[j] = ((size_t)e * NTOT + (n0 + r)) * KTOT * 2 + (size_t)((s ^ (r & 7)) * 16)
                + (size_t)kb * 2;
    }
    const char* Ac = (const char*)Abuf;
    const char* Bc = (const char*)Bt;
    const int ldst = wid * 512;   // shorts; per-issue dest = j*4096 + ldst

    floatx4 acc[8][4];
    #pragma unroll
    for (int i = 0; i < 8; i++)
        #pragma unroll
        for (int j = 0; j < 4; j++) acc[i][j] = (floatx4)0.f;

    // prologue: stage K-tile 0 into buffer 0
    #pragma unroll
    for (int j = 0; j < 4; j++)
        gload_lds16((const unsigned short*)(Ac + oA[j]), &sA[0][j * 4096 + ldst]);
    #pragma unroll
    for (int j = 0; j < 4; j++)
        gload_lds16((const unsigned short*)(Bc + oB[j]), &sB[0][j * 4096 + ldst]);
    asm volatile("s_waitcnt vmcnt(0)" ::: "memory");
    __builtin_amdgcn_s_barrier();

    #pragma unroll 1
    for (int t = 0;; t++) {
        unsigned short* sAc = sA[t & 1];
        unsigned short* sBc = sB[t & 1];
        unsigned short* sAn = sA[(t & 1) ^ 1];
        unsigned short* sBn = sB[(t & 1) ^ 1];
        const bool more = (t + 1 < NT);
        const size_t koff = (size_t)(t + 1) * 128;   // bytes: 64 bf16 per K-tile

        #pragma unroll
        for (int q = 0; q < 4; q++) {
            // front-loaded staging of tile t+1 (A at q0, B at q1)
            if (q == 0 && more) {
                #pragma unroll
                for (int j = 0; j < 4; j++)
                    gload_lds16((const unsigned short*)(Ac + oA[j] + koff),
                                sAn + j * 4096 + ldst);
            }
            if (q == 1 && more) {
                #pragma unroll
                for (int j = 0; j < 4; j++)
                    gload_lds16((const unsigned short*)(Bc + oB[j] + koff),
                                sBn + j * 4096 + ldst);
            }
            const int ks = q >> 1, mh = q & 1;
            short8 af[4], bfv[4];
            #pragma unroll
            for (int i = 0; i < 4; i++) {
                int row = wm * 128 + (mh * 4 + i) * 16 + l16;
                af[i] = *(const short8*)(sAc + row * 64 + ((ks * 4 + quad) ^ (row & 7)) * 8);
            }
            #pragma unroll
            for (int i = 0; i < 4; i++) {
                int row = wn * 64 + i * 16 + l16;
                bfv[i] = *(const short8*)(sBc + row * 64 + ((ks * 4 + quad) ^ (row & 7)) * 8);
            }
            __builtin_amdgcn_s_barrier();
            asm volatile("s_waitcnt lgkmcnt(0)" ::: "memory");
            __builtin_amdgcn_sched_barrier(0);
            __builtin_amdgcn_s_setprio(1);
            #pragma unroll
            for (int i = 0; i < 4; i++)
                #pragma unroll
                for (int ni = 0; ni < 4; ni++)
                    acc[mh * 4 + i][ni] = __builtin_amdgcn_mfma_f32_16x16x32_bf16(
                        af[i], bfv[ni], acc[mh * 4 + i][ni], 0, 0, 0);
            __builtin_amdgcn_s_setprio(0);
            __builtin_amdgcn_sched_barrier(0);
            if (q == 3 && more) asm volatile("s_waitcnt vmcnt(0)" ::: "memory");
            __builtin_amdgcn_s_barrier();
        }
        if (!more) break;
    }

    int pe1 = pbase[e + 1];
    int cnt = counts[e], pb = pbase[e];
    int colb = n0 + wn * 64 + l16;
    #pragma unroll
    for (int mi = 0; mi < 8; mi++) {
        #pragma unroll
        for (int r = 0; r < 4; r++) {
            int row = row0 + wm * 128 + mi * 16 + quad * 4 + r;
            if (SILU) {
                if (row < pe1) {            // mask expert-boundary overhang rows
                    #pragma unroll
                    for (int ni = 0; ni < 4; ni++) {
                        float v = acc[mi][ni][r];
                        float s = v / (1.f + __expf(-v));
                        Hout[(size_t)row * NTOT + colb + ni * 16] = f2bf(s);
                    }
                }
            } else {
                if (row - pb < cnt) {       // pad + overhang rows skipped
                    int tt = tids[row];
                    if (tt >= 0 && tt < BATCH) {
                        float w = twt[row];
                        #pragma unroll
                        for (int ni = 0; ni < 4; ni++)
                            atomicAdd(&Out[(size_t)tt * HID + colb + ni * 16],
                                      acc[mi][ni][r] * w);
                    }
                }
            }
        }
    }
}

// ---------- fallback (fused-convert GEMM, proven) if ws too small ----------
template <int KTOT, int NTOT, bool SILU>
__global__ __launch_bounds__(256, 2) void gemm_fused(
    const unsigned short* __restrict__ Abuf, const float* __restrict__ Wall,
    unsigned short* __restrict__ Hout, float* __restrict__ Out,
    const int* __restrict__ tids, const float* __restrict__ twt,
    const int* __restrict__ counts, const int* __restrict__ pbase) {
    __shared__ __align__(16) unsigned short sA[128][40];
    __shared__ __align__(16) unsigned short sB[128][40];
    int row0 = blockIdx.x * 128;
    if (row0 >= pbase[NEXP]) return;
    int e = 0;
    while (row0 >= pbase[e + 1]) e++;
    int n0 = blockIdx.y * 128;
    const float* Bw = Wall + (size_t)e * KTOT * NTOT;
    int tid = threadIdx.x;
    int lane = tid & 63, wid = tid >> 6;
    int wm = wid & 1, wn = wid >> 1;
    int quad = lane >> 4, l16 = lane & 15;
    floatx4 acc[4][4];
    #pragma unroll
    for (int i = 0; i < 4; i++)
        #pragma unroll
        for (int j = 0; j < 4; j++) acc[i][j] = (floatx4)0.f;
    for (int k0 = 0; k0 < KTOT; k0 += 32) {
        #pragma unroll
        for (int i = 0; i < 2; i++) {
            int q2 = tid + i * 256;
            int r = q2 >> 2, cc = (q2 & 3) * 8;
            uint4 v = *(const uint4*)(Abuf + (size_t)(row0 + r) * KTOT + k0 + cc);
            *(uint4*)(&sA[r][cc]) = v;
        }
        {
            int k = tid >> 3, n16 = (tid & 7) * 16;
            const float* bp = Bw + (size_t)(k0 + k) * NTOT + n0 + n16;
            #pragma unroll
            for (int j = 0; j < 4; j++) {
                float4 v = *(const float4*)(bp + j * 4);
                sB[n16 + j * 4 + 0][k] = f2bf(v.x);
                sB[n16 + j * 4 + 1][k] = f2bf(v.y);
                sB[n16 + j * 4 + 2][k] = f2bf(v.z);
                sB[n16 + j * 4 + 3][k] = f2bf(v.w);
            }
        }
        __syncthreads();
        short8 af[4], bfr[4];
        #pragma unroll
        for (int mi = 0; mi < 4; mi++)
            af[mi] = *(const short8*)(&sA[wm * 64 + mi * 16 + l16][quad * 8]);
        #pragma unroll
        for (int ni = 0; ni < 4; ni++)
            bfr[ni] = *(const short8*)(&sB[wn * 64 + ni * 16 + l16][quad * 8]);
        #pragma unroll
        for (int mi = 0; mi < 4; mi++)
            #pragma unroll
            for (int ni = 0; ni < 4; ni++)
                acc[mi][ni] = __builtin_amdgcn_mfma_f32_16x16x32_bf16(af[mi], bfr[ni], acc[mi][ni], 0, 0, 0);
        __syncthreads();
    }
    int cnt = counts[e], pb = pbase[e];
    #pragma unroll
    for (int mi = 0; mi < 4; mi++) {
        int rbase = row0 + wm * 64 + mi * 16 + quad * 4;
        #pragma unroll
        for (int ni = 0; ni < 4; ni++) {
            int col = n0 + wn * 64 + ni * 16 + l16;
            #pragma unroll
            for (int r = 0; r < 4; r++) {
                float v = acc[mi][ni][r];
                int row = rbase + r;
                if (SILU) {
                    float s = v / (1.f + __expf(-v));
                    Hout[(size_t)row * NTOT + col] = f2bf(s);
                } else {
                    if (row - pb < cnt) {
                        int t = tids[row];
                        if (t >= 0 && t < BATCH)
                            atomicAdd(&Out[(size_t)t * HID + col], v * twt[row]);
                    }
                }
            }
        }
    }
}

extern "C" void kernel_launch(void* const* d_in, const int* in_sizes, int n_in,
                              void* d_out, int out_size, void* d_ws, size_t ws_size,
                              hipStream_t stream) {
    const float* x = (const float*)d_in[0];
    const float* rw = (const float*)d_in[1];
    const float* w1 = (const float*)d_in[2];
    const float* w2 = (const float*)d_in[3];
    const int* idx32 = (const int*)d_in[4];
    float* out = (float*)d_out;

    char* ws = (char*)d_ws;
    int* counts = (int*)(ws + 0);
    int* cursor = (int*)(ws + 64);
    int* pbase  = (int*)(ws + 128);
    int* fmt    = (int*)(ws + 192);
    int* mte    = (int*)(ws + 256);
    int* mtr    = (int*)(ws + 512);
    int* ntiles = (int*)(ws + 768);
    int* tids   = (int*)(ws + 4096);
    float* twt  = (float*)(ws + 4096 + MAXROWS * 4);

    size_t off = 65536;
    unsigned short* Apk  = (unsigned short*)(ws + off);  off += (size_t)MAXROWS * HID * 2;    // 10.5 MB
    unsigned short* Hact = (unsigned short*)(ws + off);  off += (size_t)MAXROWS * FFN * 2;    // 41.9 MB
    unsigned short* w1t  = (unsigned short*)(ws + off);  off += (size_t)NEXP * HID * FFN * 2; // 67.1 MB
    unsigned short* w2t  = (unsigned short*)(ws + off);  off += (size_t)NEXP * FFN * HID * 2; // 67.1 MB
    const bool big = ws_size >= off;   // constant per session -> graph-safe branch

    // zero meta + tids/twt + Apk in one shot (padding rows become true zeros)
    hipMemsetAsync(d_ws, 0, 65536 + (size_t)MAXROWS * HID * 2, stream);
    hipMemsetAsync(d_out, 0, (size_t)out_size * sizeof(float), stream);

    route_all<<<1, 1024, 0, stream>>>(idx32, fmt, counts, pbase, cursor, mte, mtr, ntiles);
    scatter_gather<<<BATCH, 128, 0, stream>>>(x, rw, idx32, fmt, cursor, tids, twt, Apk);

    if (big) {
        conv_transpose<<<dim3(FFN / 64, HID / 64, NEXP), 256, 0, stream>>>(w1, w1t, HID, FFN);
        conv_transpose<<<dim3(HID / 64, FFN / 64, NEXP), 256, 0, stream>>>(w2, w2t, FFN, HID);
        gemm8p<HID, FFN, true, 1><<<dim3(MT256, FFN / 256, 1), 512, 0, stream>>>(
            Apk, w1t, Hact, nullptr, tids, twt, counts, pbase, mte, mtr, ntiles);
        gemm8p<FFN, HID, false, 4><<<dim3(MT256, HID / 256, 4), 512, 0, stream>>>(
            Hact, w2t, nullptr, out, tids, twt, counts, pbase, mte, mtr, ntiles);
    } else {
        gemm_fused<HID, FFN, true><<<dim3(MTILES, FFN / 128), 256, 0, stream>>>(
            Apk, w1, Hact, nullptr, tids, twt, counts, pbase);
        gemm_fused<FFN, HID, false><<<dim3(MTILES, HID / 128), 256, 0, stream>>>(
            Hact, w2, nullptr, out, tids, twt, counts, pbase);
    }
}

// Round 5
// 601.774 us; speedup vs baseline: 1.0376x; 1.0376x over previous
//
#include <hip/hip_runtime.h>

#define BATCH 2048
#define HID 1024
#define FFN 4096
#define NEXP 8
#define MAXROWS 5120   // sum ceil(count_e/128)*128 <= 4096 + 8*127 -> round up
#define MTILES 40      // MAXROWS/128

typedef __attribute__((ext_vector_type(8))) short short8;
typedef __attribute__((ext_vector_type(4))) float floatx4;

// fp32 -> bf16 round-to-nearest-even
static __device__ inline unsigned short f2bf(float f) {
    unsigned int u = __float_as_uint(f);
    unsigned int r = (u + 0x7fffu + ((u >> 16) & 1u)) >> 16;
    return (unsigned short)r;
}

static __device__ inline int load_idx(const int* idx32, int flat, int is32) {
    return is32 ? idx32[flat] : idx32[2 * flat];  // int64 little-endian low word
}

// async global -> LDS DMA, 16B/lane; LDS dest wave-uniform base + lane*16.
static __device__ inline void gload_lds16(const unsigned short* g, unsigned short* l) {
    __builtin_amdgcn_global_load_lds(
        (const __attribute__((address_space(1))) unsigned int*)g,
        (__attribute__((address_space(3))) unsigned int*)l,
        16, 0, 0);
}

// fused: detect int32/int64 layout, per-expert counts, padded prefix sum.
__global__ void route_all(const int* __restrict__ idx32, int* __restrict__ fmt,
                          int* __restrict__ counts, int* __restrict__ pbase,
                          int* __restrict__ cursor) {
    __shared__ int s_cnt[NEXP];
    __shared__ int s_fmt;
    int t = threadIdx.x;  // 1024 threads
    if (t < NEXP) s_cnt[t] = 0;
    if (t == 0) s_fmt = 0;
    __syncthreads();
    int bad = 0;
    for (int i = t; i < BATCH; i += 1024)       // odd words of first BATCH values
        if (idx32[2 * i + 1] != 0) bad = 1;     // in-bounds for both layouts
    if (bad) atomicOr(&s_fmt, 1);               // nonzero odd word -> plain int32
    __syncthreads();
    int is32 = s_fmt;
    for (int b = t; b < BATCH; b += 1024) {
        int e0 = load_idx(idx32, 2 * b, is32);
        int e1 = load_idx(idx32, 2 * b + 1, is32);
        atomicAdd(&s_cnt[e0], 1);
        if (e1 != e0) atomicAdd(&s_cnt[e1], 1);
    }
    __syncthreads();
    if (t == 0) {
        fmt[0] = is32;
        int acc = 0;
        for (int e = 0; e < NEXP; e++) {
            counts[e] = s_cnt[e];
            pbase[e] = acc;
            cursor[e] = acc;
            acc += ((s_cnt[e] + 127) >> 7) << 7;
        }
        pbase[NEXP] = acc;
    }
}

__global__ void scatter_gather(const float* __restrict__ x, const float* __restrict__ rw,
                               const int* __restrict__ idx32, const int* __restrict__ fmt,
                               int* __restrict__ cursor, int* __restrict__ tids,
                               float* __restrict__ twt, unsigned short* __restrict__ Apk) {
    __shared__ int s_slot[2];
    __shared__ int s_n;
    int b = blockIdx.x;
    if (threadIdx.x == 0) {
        int is32 = fmt[0];
        int e0 = load_idx(idx32, 2 * b, is32);
        int e1 = load_idx(idx32, 2 * b + 1, is32);
        float w0 = rw[2 * b], w1 = rw[2 * b + 1];
        int n, ee[2];
        float ww[2];
        if (e0 == e1) { n = 1; ee[0] = e0; ww[0] = w0 + w1; }
        else { n = 2; ee[0] = e0; ww[0] = w0; ee[1] = e1; ww[1] = w1; }
        for (int j = 0; j < n; j++) {
            int slot = atomicAdd(&cursor[ee[j]], 1);
            s_slot[j] = slot;
            tids[slot] = b;
            twt[slot] = ww[j];
        }
        s_n = n;
    }
    __syncthreads();
    int n = s_n;
    const float4* src = (const float4*)(x + (size_t)b * HID);
    for (int j = 0; j < n; j++) {
        unsigned short* dst = Apk + (size_t)s_slot[j] * HID;
        #pragma unroll
        for (int r = 0; r < 2; r++) {
            int i = threadIdx.x + r * 128;
            float4 v = src[i];
            union { unsigned short u[4]; uint2 q; } p;
            p.u[0] = f2bf(v.x); p.u[1] = f2bf(v.y);
            p.u[2] = f2bf(v.z); p.u[3] = f2bf(v.w);
            *(uint2*)(dst + i * 4) = p.q;
        }
    }
}

// convert fp32 W[E][K][N] -> bf16 Wt[E][N][K] (transpose via 64x64 LDS tile)
__global__ void conv_transpose(const float* __restrict__ W, unsigned short* __restrict__ Wt,
                               int K, int N) {
    __shared__ unsigned short sT[64][65];
    int e = blockIdx.z;
    int kt = blockIdx.y * 64, nt = blockIdx.x * 64;
    const float* src = W + ((size_t)e * K + kt) * N + nt;
    #pragma unroll
    for (int i = 0; i < 4; i++) {
        int t = threadIdx.x + i * 256;          // 0..1023, 64 rows x 16 float4
        int r = t >> 4, c4 = (t & 15) * 4;
        float4 v = *(const float4*)(src + (size_t)r * N + c4);
        sT[c4 + 0][r] = f2bf(v.x);
        sT[c4 + 1][r] = f2bf(v.y);
        sT[c4 + 2][r] = f2bf(v.z);
        sT[c4 + 3][r] = f2bf(v.w);
    }
    __syncthreads();
    #pragma unroll
    for (int i = 0; i < 2; i++) {
        int u = threadIdx.x + i * 256;          // 0..511, 64 rows x 8 uint4
        int n = u >> 3, k8 = (u & 7) * 8;
        union { unsigned short h[8]; uint4 q; } p;
        #pragma unroll
        for (int j = 0; j < 8; j++) p.h[j] = sT[n][k8 + j];
        *(uint4*)(Wt + ((size_t)e * N + nt + n) * K + kt + k8) = p.q;
    }
}

// 128x128 tile, BK=32, TRIPLE-buffered LDS staged by global_load_lds width=16,
// counted vmcnt(4) (never 0 in steady state), ONE raw s_barrier per K-step.
// Loads for tile k+2 are issued at iter k and waited at iter k+1's end -> two
// full iterations of latency cover (the round-0 reg-staged loop covered only
// its own MFMA block; round-1's __syncthreads drained vmcnt(0) every iter).
// LDS stays LINEAR for the DMA (rule: dest = uniform base + lane*16); the
// bank swizzle (16B slot s of row r holds global k-slot s^((r>>1)&3)) is
// applied on the GLOBAL source address and mirrored on the read side --
// 0 bank conflicts verified in r2 with this exact XOR.
// A: bf16 [rows][KTOT], Bt: bf16 [E][NTOT][KTOT].
template <int KTOT, int NTOT, bool SILU, int KSPLIT>
__global__ __launch_bounds__(256, 3) void gemm_p3(
    const unsigned short* __restrict__ Abuf, const unsigned short* __restrict__ Bt,
    unsigned short* __restrict__ Hout, float* __restrict__ Out,
    const int* __restrict__ tids, const float* __restrict__ twt,
    const int* __restrict__ counts, const int* __restrict__ pbase) {
    __shared__ __align__(16) unsigned short sA[3][128 * 32];
    __shared__ __align__(16) unsigned short sB[3][128 * 32];

    int row0 = blockIdx.x * 128;
    if (row0 >= pbase[NEXP]) return;
    int e = 0;
    while (row0 >= pbase[e + 1]) e++;
    int n0 = blockIdx.y * 128;
    constexpr int KCH = KTOT / KSPLIT;
    constexpr int NK = KCH / 32;     // 32 for both GEMMs; pipeline needs NK>=3
    int kb = blockIdx.z * KCH;

    const unsigned short* Aw = Abuf + (size_t)row0 * KTOT + kb;
    const unsigned short* Bw = Bt + ((size_t)e * NTOT + n0) * KTOT + kb;

    int tid = threadIdx.x;
    int lane = tid & 63, wid = tid >> 6;
    int wm = wid & 1, wn = wid >> 1;
    int quad = lane >> 4, l16 = lane & 15;

    // DMA map: 512 16B-chunks per 128x32 tile; wave wid covers chunks
    // [wid*128, wid*128+128) via 2 issues (64 lanes x 16B each).
    // chunk c -> LDS (linear) slot c; global source row c>>2, k-slot
    // (c&3) ^ (((c>>2)>>1)&3)  [pre-swizzled source, m173 pattern].
    int c0 = wid * 128 + lane, c1 = c0 + 64;
    int cr0 = c0 >> 2, cs0 = c0 & 3;
    int cr1 = c1 >> 2, cs1 = c1 & 3;
    const unsigned short* gA0 = Aw + (size_t)cr0 * KTOT + (cs0 ^ ((cr0 >> 1) & 3)) * 8;
    const unsigned short* gA1 = Aw + (size_t)cr1 * KTOT + (cs1 ^ ((cr1 >> 1) & 3)) * 8;
    const unsigned short* gB0 = Bw + (size_t)cr0 * KTOT + (cs0 ^ ((cr0 >> 1) & 3)) * 8;
    const unsigned short* gB1 = Bw + (size_t)cr1 * KTOT + (cs1 ^ ((cr1 >> 1) & 3)) * 8;
    const int d0 = wid * 1024, d1 = wid * 1024 + 512;   // shorts (wave-uniform)
    // fragment read: 16B slot quad of row R lives at slot quad^((R>>1)&3);
    // only l16 contributes to (R>>1)&3 (wm*64, mi*16 are multiples of 8 in R>>1)
    const int sq = (quad ^ ((l16 >> 1) & 3)) * 8;

    floatx4 acc[4][4];
    #pragma unroll
    for (int i = 0; i < 4; i++)
        #pragma unroll
        for (int j = 0; j < 4; j++) acc[i][j] = (floatx4)0.f;

    // prologue: stage tiles 0 and 1 (8 issues/wave outstanding)
    gload_lds16(gA0,      &sA[0][d0]); gload_lds16(gA1,      &sA[0][d1]);
    gload_lds16(gB0,      &sB[0][d0]); gload_lds16(gB1,      &sB[0][d1]);
    gload_lds16(gA0 + 32, &sA[1][d0]); gload_lds16(gA1 + 32, &sA[1][d1]);
    gload_lds16(gB0 + 32, &sB[1][d0]); gload_lds16(gB1 + 32, &sB[1][d1]);
    asm volatile("s_waitcnt vmcnt(4)" ::: "memory");   // tile 0 resident
    __builtin_amdgcn_s_barrier();
    __builtin_amdgcn_sched_barrier(0);

    int cur = 0, wb = 2;
    #pragma unroll
    for (int k = 0; k < NK; k++) {
        // issue tile k+2 into the buffer freed by the barrier that closed
        // iter k-1 (its reads of tile k-1 are complete block-wide).
        if (k + 2 < NK) {
            int ko = (k + 2) * 32;
            gload_lds16(gA0 + ko, &sA[wb][d0]); gload_lds16(gA1 + ko, &sA[wb][d1]);
            gload_lds16(gB0 + ko, &sB[wb][d0]); gload_lds16(gB1 + ko, &sB[wb][d1]);
        }
        short8 af[4], bfv[4];
        #pragma unroll
        for (int mi = 0; mi < 4; mi++)
            af[mi] = *(const short8*)(sA[cur] + (wm * 64 + mi * 16 + l16) * 32 + sq);
        #pragma unroll
        for (int ni = 0; ni < 4; ni++)
            bfv[ni] = *(const short8*)(sB[cur] + (wn * 64 + ni * 16 + l16) * 32 + sq);
        #pragma unroll
        for (int mi = 0; mi < 4; mi++)
            #pragma unroll
            for (int ni = 0; ni < 4; ni++)
                acc[mi][ni] = __builtin_amdgcn_mfma_f32_16x16x32_bf16(af[mi], bfv[ni], acc[mi][ni], 0, 0, 0);
        if (k + 1 == NK) break;
        // tile k+1 must be resident block-wide before next iter reads it.
        if (k + 2 < NK) asm volatile("s_waitcnt vmcnt(4)" ::: "memory");
        else            asm volatile("s_waitcnt vmcnt(0)" ::: "memory");
        __builtin_amdgcn_s_barrier();
        __builtin_amdgcn_sched_barrier(0);
        cur = (cur == 2) ? 0 : cur + 1;
        wb  = (wb  == 2) ? 0 : wb + 1;
    }

    int cnt = counts[e], pb = pbase[e];
    #pragma unroll
    for (int mi = 0; mi < 4; mi++) {
        int rbase = row0 + wm * 64 + mi * 16 + quad * 4;
        #pragma unroll
        for (int ni = 0; ni < 4; ni++) {
            int col = n0 + wn * 64 + ni * 16 + l16;
            #pragma unroll
            for (int r = 0; r < 4; r++) {
                float v = acc[mi][ni][r];
                int row = rbase + r;
                if (SILU) {
                    float s = v / (1.f + __expf(-v));
                    Hout[(size_t)row * NTOT + col] = f2bf(s);
                } else {
                    if (row - pb < cnt) {
                        int t = tids[row];
                        if (t >= 0 && t < BATCH)
                            atomicAdd(&Out[(size_t)t * HID + col], v * twt[row]);
                    }
                }
            }
        }
    }
}

// ---------- fallback (fused-convert GEMM, proven) if ws too small ----------
template <int KTOT, int NTOT, bool SILU>
__global__ __launch_bounds__(256, 2) void gemm_fused(
    const unsigned short* __restrict__ Abuf, const float* __restrict__ Wall,
    unsigned short* __restrict__ Hout, float* __restrict__ Out,
    const int* __restrict__ tids, const float* __restrict__ twt,
    const int* __restrict__ counts, const int* __restrict__ pbase) {
    __shared__ __align__(16) unsigned short sA[128][40];
    __shared__ __align__(16) unsigned short sB[128][40];
    int row0 = blockIdx.x * 128;
    if (row0 >= pbase[NEXP]) return;
    int e = 0;
    while (row0 >= pbase[e + 1]) e++;
    int n0 = blockIdx.y * 128;
    const float* Bw = Wall + (size_t)e * KTOT * NTOT;
    int tid = threadIdx.x;
    int lane = tid & 63, wid = tid >> 6;
    int wm = wid & 1, wn = wid >> 1;
    int quad = lane >> 4, l16 = lane & 15;
    floatx4 acc[4][4];
    #pragma unroll
    for (int i = 0; i < 4; i++)
        #pragma unroll
        for (int j = 0; j < 4; j++) acc[i][j] = (floatx4)0.f;
    for (int k0 = 0; k0 < KTOT; k0 += 32) {
        #pragma unroll
        for (int i = 0; i < 2; i++) {
            int q2 = tid + i * 256;
            int r = q2 >> 2, cc = (q2 & 3) * 8;
            uint4 v = *(const uint4*)(Abuf + (size_t)(row0 + r) * KTOT + k0 + cc);
            *(uint4*)(&sA[r][cc]) = v;
        }
        {
            int k = tid >> 3, n16 = (tid & 7) * 16;
            const float* bp = Bw + (size_t)(k0 + k) * NTOT + n0 + n16;
            #pragma unroll
            for (int j = 0; j < 4; j++) {
                float4 v = *(const float4*)(bp + j * 4);
                sB[n16 + j * 4 + 0][k] = f2bf(v.x);
                sB[n16 + j * 4 + 1][k] = f2bf(v.y);
                sB[n16 + j * 4 + 2][k] = f2bf(v.z);
                sB[n16 + j * 4 + 3][k] = f2bf(v.w);
            }
        }
        __syncthreads();
        short8 af[4], bfr[4];
        #pragma unroll
        for (int mi = 0; mi < 4; mi++)
            af[mi] = *(const short8*)(&sA[wm * 64 + mi * 16 + l16][quad * 8]);
        #pragma unroll
        for (int ni = 0; ni < 4; ni++)
            bfr[ni] = *(const short8*)(&sB[wn * 64 + ni * 16 + l16][quad * 8]);
        #pragma unroll
        for (int mi = 0; mi < 4; mi++)
            #pragma unroll
            for (int ni = 0; ni < 4; ni++)
                acc[mi][ni] = __builtin_amdgcn_mfma_f32_16x16x32_bf16(af[mi], bfr[ni], acc[mi][ni], 0, 0, 0);
        __syncthreads();
    }
    int cnt = counts[e], pb = pbase[e];
    #pragma unroll
    for (int mi = 0; mi < 4; mi++) {
        int rbase = row0 + wm * 64 + mi * 16 + quad * 4;
        #pragma unroll
        for (int ni = 0; ni < 4; ni++) {
            int col = n0 + wn * 64 + ni * 16 + l16;
            #pragma unroll
            for (int r = 0; r < 4; r++) {
                float v = acc[mi][ni][r];
                int row = rbase + r;
                if (SILU) {
                    float s = v / (1.f + __expf(-v));
                    Hout[(size_t)row * NTOT + col] = f2bf(s);
                } else {
                    if (row - pb < cnt) {
                        int t = tids[row];
                        if (t >= 0 && t < BATCH)
                            atomicAdd(&Out[(size_t)t * HID + col], v * twt[row]);
                    }
                }
            }
        }
    }
}

extern "C" void kernel_launch(void* const* d_in, const int* in_sizes, int n_in,
                              void* d_out, int out_size, void* d_ws, size_t ws_size,
                              hipStream_t stream) {
    const float* x = (const float*)d_in[0];
    const float* rw = (const float*)d_in[1];
    const float* w1 = (const float*)d_in[2];
    const float* w2 = (const float*)d_in[3];
    const int* idx32 = (const int*)d_in[4];
    float* out = (float*)d_out;

    char* ws = (char*)d_ws;
    int* counts = (int*)(ws + 0);
    int* cursor = (int*)(ws + 64);
    int* pbase  = (int*)(ws + 128);
    int* fmt    = (int*)(ws + 192);
    int* tids   = (int*)(ws + 4096);
    float* twt  = (float*)(ws + 4096 + MAXROWS * 4);

    size_t off = 65536;
    unsigned short* Apk  = (unsigned short*)(ws + off);  off += (size_t)MAXROWS * HID * 2;    // 10.5 MB
    unsigned short* Hact = (unsigned short*)(ws + off);  off += (size_t)MAXROWS * FFN * 2;    // 41.9 MB
    unsigned short* w1t  = (unsigned short*)(ws + off);  off += (size_t)NEXP * HID * FFN * 2; // 67.1 MB
    unsigned short* w2t  = (unsigned short*)(ws + off);  off += (size_t)NEXP * FFN * HID * 2; // 67.1 MB
    const bool big = ws_size >= off;   // constant per session -> graph-safe branch

    // zero meta + tids/twt + Apk in one shot (padding rows become true zeros)
    hipMemsetAsync(d_ws, 0, 65536 + (size_t)MAXROWS * HID * 2, stream);
    hipMemsetAsync(d_out, 0, (size_t)out_size * sizeof(float), stream);

    route_all<<<1, 1024, 0, stream>>>(idx32, fmt, counts, pbase, cursor);
    scatter_gather<<<BATCH, 128, 0, stream>>>(x, rw, idx32, fmt, cursor, tids, twt, Apk);

    if (big) {
        conv_transpose<<<dim3(FFN / 64, HID / 64, NEXP), 256, 0, stream>>>(w1, w1t, HID, FFN);
        conv_transpose<<<dim3(HID / 64, FFN / 64, NEXP), 256, 0, stream>>>(w2, w2t, FFN, HID);
        gemm_p3<HID, FFN, true, 1><<<dim3(MTILES, FFN / 128, 1), 256, 0, stream>>>(
            Apk, w1t, Hact, nullptr, tids, twt, counts, pbase);
        gemm_p3<FFN, HID, false, 4><<<dim3(MTILES, HID / 128, 4), 256, 0, stream>>>(
            Hact, w2t, nullptr, out, tids, twt, counts, pbase);
    } else {
        gemm_fused<HID, FFN, true><<<dim3(MTILES, FFN / 128), 256, 0, stream>>>(
            Apk, w1, Hact, nullptr, tids, twt, counts, pbase);
        gemm_fused<FFN, HID, false><<<dim3(MTILES, HID / 128), 256, 0, stream>>>(
            Hact, w2, nullptr, out, tids, twt, counts, pbase);
    }
}